// Round 3
// baseline (603.252 us; speedup 1.0000x reference)
//
#include <hip/hip_runtime.h>

// GCN 2-layer + mean-pool + readout. CSR-gather, bf16 features, collapsed layer 2:
//   h1[n] = relu( norm_in[n] * (sum_{e:dst=n} norm_out[src_e]*x[src_e]) @ W1 + b1 )
//   out   = ((1/N) * sum_n (norm_out[n]*c_raw[n]) * h1[n]) @ W2 + b2 @ Wr^T + br
//   c_raw[u] = sum_{e:src=u} norm_in[dst_e]
// norms computed on the fly as rsqrt(max(deg,1)).

constexpr int NN = 50000;
constexpr int NE = 800000;

// ws layout (dword offsets)
constexpr int OFF_DEG_OUT = 0;        // int[50000]   zeroed
constexpr int OFF_DEG_IN  = 50000;    // int[50000]   zeroed
constexpr int OFF_CRAW    = 100000;   // float[50000] zeroed
constexpr int OFF_SVEC    = 150000;   // float[96]    zeroed
constexpr int OFF_TILECTR = 150100;   // int[1]       zeroed
constexpr int OFF_ROW_PTR = 150256;   // int[50001]
constexpr int OFF_CURSOR  = 200260;   // int[50000]
constexpr int OFF_EDGEREC = 250260;   // int2[800000]  (offset even -> 8B aligned)
constexpr int OFF_FEATB   = 1850260;  // ushort[4800000] (offset %4==0 -> 16B aligned)
constexpr size_t ZERO_BYTES = (size_t)150256 * 4;   // 601 KB

__device__ __forceinline__ float bf2f(unsigned short u) {
  return __uint_as_float(((unsigned int)u) << 16);
}

// f32 -> packed bf16 (RNE), 8 floats/thread
__global__ void k_cast(const float* __restrict__ f, uint4* __restrict__ fb) {
  int i = blockIdx.x * blockDim.x + threadIdx.x;
  if (i < NN * 96 / 8) {
    const float4* f4 = (const float4*)f;
    float4 a = f4[2 * i], b = f4[2 * i + 1];
    auto cv = [](float x) -> unsigned int {
      unsigned int u = __float_as_uint(x);
      return (u + 0x7FFFu + ((u >> 16) & 1u)) >> 16;
    };
    uint4 o;
    o.x = cv(a.x) | (cv(a.y) << 16);
    o.y = cv(a.z) | (cv(a.w) << 16);
    o.z = cv(b.x) | (cv(b.y) << 16);
    o.w = cv(b.z) | (cv(b.w) << 16);
    fb[i] = o;
  }
}

__global__ void k_deg(const int4* __restrict__ src4, const int4* __restrict__ dst4,
                      int* __restrict__ deg_out, int* __restrict__ deg_in) {
  int i = blockIdx.x * blockDim.x + threadIdx.x;
  if (i < NE / 4) {
    int4 s = src4[i], d = dst4[i];
    atomicAdd(&deg_out[s.x], 1); atomicAdd(&deg_out[s.y], 1);
    atomicAdd(&deg_out[s.z], 1); atomicAdd(&deg_out[s.w], 1);
    atomicAdd(&deg_in[d.x], 1);  atomicAdd(&deg_in[d.y], 1);
    atomicAdd(&deg_in[d.z], 1);  atomicAdd(&deg_in[d.w], 1);
  }
}

// Exclusive scan of deg_in -> row_ptr AND cursor (pre-initialized). One block of 512.
__global__ void k_scan(const int* __restrict__ deg_in,
                       int* __restrict__ row_ptr, int* __restrict__ cursor) {
  __shared__ int part[512];
  const int CH = 98;                 // 512*98 = 50176 >= NN
  int t = threadIdx.x;
  int base = t * CH, s = 0;
  for (int i = 0; i < CH; ++i) {
    int idx = base + i;
    if (idx < NN) s += deg_in[idx];
  }
  part[t] = s;
  __syncthreads();
  for (int off = 1; off < 512; off <<= 1) {
    int v = (t >= off) ? part[t - off] : 0;
    __syncthreads();
    part[t] += v;
    __syncthreads();
  }
  int run = part[t] - s;
  for (int i = 0; i < CH; ++i) {
    int idx = base + i;
    if (idx < NN) { row_ptr[idx] = run; cursor[idx] = run; run += deg_in[idx]; }
  }
  if (t == 511) row_ptr[NN] = part[511];
}

// Counting-sort by dst into packed records {src, norm_out[src]}; accumulate c_raw.
__global__ void k_scatter(const int* __restrict__ src, const int* __restrict__ dst,
                          const int* __restrict__ deg_out, const int* __restrict__ deg_in,
                          int* __restrict__ cursor, int2* __restrict__ erec,
                          float* __restrict__ c_raw) {
  int e = blockIdx.x * blockDim.x + threadIdx.x;
  if (e < NE) {
    int d = dst[e], s = src[e];
    int pos = atomicAdd(&cursor[d], 1);
    float w = rsqrtf((float)max(deg_out[s], 1));
    int2 r; r.x = s; r.y = __float_as_int(w);
    erec[pos] = r;
    atomicAdd(&c_raw[s], rsqrtf((float)max(deg_in[d], 1)));
  }
}

// Fused gather (bf16) + W1 matmul + relu + weighted global sum.
// 512 threads = 16 half-wave groups; NT=4 nodes per dynamically-claimed tile.
#define NT 4
__global__ __launch_bounds__(512, 8)
void k_fused(const unsigned short* __restrict__ featb,
             const int* __restrict__ deg_in, const int* __restrict__ deg_out,
             const float* __restrict__ c_raw,
             const int* __restrict__ row_ptr, const int2* __restrict__ erec,
             const float* __restrict__ W1, const float* __restrict__ b1,
             int* __restrict__ tilectr, float* __restrict__ svec) {
  __shared__ float W1s[96 * 96];
  __shared__ float b1s[96];
  __shared__ float red[96];
  int tid = threadIdx.x;
  for (int i = tid; i < 96 * 96 / 4; i += 512)
    ((float4*)W1s)[i] = ((const float4*)W1)[i];
  if (tid < 96) { b1s[tid] = b1[tid]; red[tid] = 0.0f; }
  __syncthreads();

  const int l = tid & 31;
  const int NTILES = (NN + NT - 1) / NT;
  float accs0 = 0.f, accs1 = 0.f, accs2 = 0.f;

  for (;;) {
    int tile = 0;
    if (l == 0) tile = atomicAdd(tilectr, 1);
    tile = __shfl(tile, 0, 32);
    if (tile >= NTILES) break;

    float v[NT][3];
#pragma unroll
    for (int j = 0; j < NT; ++j) { v[j][0] = v[j][1] = v[j][2] = 0.f; }

    // ---- gather (bf16 rows, coalesced ushort loads) ----
#pragma unroll
    for (int j = 0; j < NT; ++j) {
      int n = tile * NT + j;
      if (n < NN) {
        int e0 = row_ptr[n], e1 = row_ptr[n + 1];
        for (int base = e0; base < e1; base += 32) {
          int idx = base + l;
          int2 er = make_int2(0, 0);
          if (idx < e1) er = erec[idx];
          int cnt = min(32, e1 - base);
          int t2 = 0;
          for (; t2 + 1 < cnt; t2 += 2) {        // 2-edge unroll: 6 loads in flight
            int   s0 = __shfl(er.x, t2, 32),                 s1 = __shfl(er.x, t2 + 1, 32);
            float w0 = __shfl(__int_as_float(er.y), t2, 32), w1 = __shfl(__int_as_float(er.y), t2 + 1, 32);
            const unsigned short* r0 = featb + (size_t)s0 * 96;
            const unsigned short* r1 = featb + (size_t)s1 * 96;
            float x0 = bf2f(r0[l]), x1 = bf2f(r0[l + 32]), x2 = bf2f(r0[l + 64]);
            float y0 = bf2f(r1[l]), y1 = bf2f(r1[l + 32]), y2 = bf2f(r1[l + 64]);
            v[j][0] = fmaf(w0, x0, fmaf(w1, y0, v[j][0]));
            v[j][1] = fmaf(w0, x1, fmaf(w1, y1, v[j][1]));
            v[j][2] = fmaf(w0, x2, fmaf(w1, y2, v[j][2]));
          }
          if (t2 < cnt) {
            int   s0 = __shfl(er.x, t2, 32);
            float w0 = __shfl(__int_as_float(er.y), t2, 32);
            const unsigned short* r0 = featb + (size_t)s0 * 96;
            v[j][0] = fmaf(w0, bf2f(r0[l]),      v[j][0]);
            v[j][1] = fmaf(w0, bf2f(r0[l + 32]), v[j][1]);
            v[j][2] = fmaf(w0, bf2f(r0[l + 64]), v[j][2]);
          }
        }
        float ni = rsqrtf((float)max(deg_in[n], 1));
        v[j][0] *= ni; v[j][1] *= ni; v[j][2] *= ni;
      }
    }

    // ---- matmul + relu + weighted sum ----
    float h[NT][3];
#pragma unroll
    for (int j = 0; j < NT; ++j) {
      h[j][0] = b1s[l]; h[j][1] = b1s[l + 32]; h[j][2] = b1s[l + 64];
    }
#pragma unroll
    for (int kb = 0; kb < 3; ++kb) {
#pragma unroll
      for (int kk = 0; kk < 32; ++kk) {
        int k = kb * 32 + kk;
        float w0 = W1s[k * 96 + l];
        float w1 = W1s[k * 96 + l + 32];
        float w2 = W1s[k * 96 + l + 64];
#pragma unroll
        for (int j = 0; j < NT; ++j) {
          float vk = __shfl(v[j][kb], kk, 32);
          h[j][0] = fmaf(vk, w0, h[j][0]);
          h[j][1] = fmaf(vk, w1, h[j][1]);
          h[j][2] = fmaf(vk, w2, h[j][2]);
        }
      }
    }
#pragma unroll
    for (int j = 0; j < NT; ++j) {
      int n = tile * NT + j;
      if (n < NN) {
        float cw = rsqrtf((float)max(deg_out[n], 1)) * c_raw[n];
        accs0 += cw * fmaxf(h[j][0], 0.f);
        accs1 += cw * fmaxf(h[j][1], 0.f);
        accs2 += cw * fmaxf(h[j][2], 0.f);
      }
    }
  }

  atomicAdd(&red[l],      accs0);
  atomicAdd(&red[l + 32], accs1);
  atomicAdd(&red[l + 64], accs2);
  __syncthreads();
  if (tid < 96) atomicAdd(&svec[tid], red[tid]);
}

// hg = (svec/N) @ W2 + b2 ; out = hg @ Wr^T + br
__global__ void k_final(const float* __restrict__ svec,
                        const float* __restrict__ W2, const float* __restrict__ b2,
                        const float* __restrict__ Wr, const float* __restrict__ br,
                        float* __restrict__ out) {
  __shared__ float hg[96];
  int j = threadIdx.x;
  if (j < 96) {
    float acc = b2[j];
    const float invN = 1.0f / (float)NN;
    for (int k = 0; k < 96; ++k)
      acc = fmaf(svec[k] * invN, W2[k * 96 + j], acc);
    hg[j] = acc;
  }
  __syncthreads();
  if (j < 8) {
    float acc = br[j];
    for (int k = 0; k < 96; ++k)
      acc = fmaf(hg[k], Wr[j * 96 + k], acc);
    out[j] = acc;
  }
}

extern "C" void kernel_launch(void* const* d_in, const int* in_sizes, int n_in,
                              void* d_out, int out_size, void* d_ws, size_t ws_size,
                              hipStream_t stream) {
  const float* feats = (const float*)d_in[0];
  const int*   src   = (const int*)d_in[1];
  const int*   dst   = (const int*)d_in[2];
  const float* W1    = (const float*)d_in[3];
  const float* b1    = (const float*)d_in[4];
  const float* W2    = (const float*)d_in[5];
  const float* b2    = (const float*)d_in[6];
  const float* Wr    = (const float*)d_in[7];
  const float* br    = (const float*)d_in[8];
  float* out = (float*)d_out;

  int*   wsi = (int*)d_ws;
  float* wsf = (float*)d_ws;
  int*   deg_out = wsi + OFF_DEG_OUT;
  int*   deg_in  = wsi + OFF_DEG_IN;
  float* c_raw   = wsf + OFF_CRAW;
  float* svec    = wsf + OFF_SVEC;
  int*   tilectr = wsi + OFF_TILECTR;
  int*   row_ptr = wsi + OFF_ROW_PTR;
  int*   cursor  = wsi + OFF_CURSOR;
  int2*  erec    = (int2*)(wsi + OFF_EDGEREC);
  unsigned short* featb = (unsigned short*)(wsi + OFF_FEATB);

  hipMemsetAsync(d_ws, 0, ZERO_BYTES, stream);

  k_cast<<<(NN * 96 / 8 + 255) / 256, 256, 0, stream>>>(feats, (uint4*)featb);
  k_deg<<<(NE / 4 + 255) / 256, 256, 0, stream>>>((const int4*)src, (const int4*)dst,
                                                  deg_out, deg_in);
  k_scan<<<1, 512, 0, stream>>>(deg_in, row_ptr, cursor);
  k_scatter<<<(NE + 255) / 256, 256, 0, stream>>>(src, dst, deg_out, deg_in,
                                                  cursor, erec, c_raw);
  k_fused<<<1024, 512, 0, stream>>>(featb, deg_in, deg_out, c_raw,
                                    row_ptr, erec, W1, b1, tilectr, svec);
  k_final<<<1, 128, 0, stream>>>(svec, W2, b2, Wr, br, out);
}